// Round 1
// baseline (529.326 us; speedup 1.0000x reference)
//
#include <hip/hip_runtime.h>

#define NN 5000
#define NF 4
#define NT 12
#define NC 600
#define NE 160000
#define FT 48   // NF*NT

// ws layout (float offsets):
//   dis   [0,      5000)
//   agg   [5000,   245000)
//   Mz    [245000, 247400)
//   betaz [247400, 248000)
//   Mh    [248000, 250400)
//   betah [250400, 251000)

__global__ void k_deg_init(float* __restrict__ deg) {
    int i = blockIdx.x * blockDim.x + threadIdx.x;
    if (i < NN) deg[i] = 1.0f;   // self-loop weight
}

__global__ void k_deg_acc(const int* __restrict__ ei, const float* __restrict__ w,
                          float* __restrict__ deg) {
    int e = blockIdx.x * blockDim.x + threadIdx.x;
    if (e < NE) atomicAdd(&deg[ei[NE + e]], w[e]);   // col = target
}

__global__ void k_dis(float* __restrict__ deg) {
    int i = blockIdx.x * blockDim.x + threadIdx.x;
    if (i < NN) { float d = deg[i]; deg[i] = d > 0.f ? rsqrtf(d) : 0.f; }
}

// agg init with self-loop contribution: agg[n,ft] = dis[n]^2 * x[n,ft]
__global__ void k_self(const float* __restrict__ x, const float* __restrict__ dis,
                       float* __restrict__ agg) {
    int idx = blockIdx.x * blockDim.x + threadIdx.x;
    if (idx < NN * FT) {
        int n = idx / FT;
        float di = dis[n];
        agg[idx] = di * di * x[idx];
    }
}

__global__ void k_edge(const int* __restrict__ ei, const float* __restrict__ w,
                       const float* __restrict__ x, const float* __restrict__ dis,
                       float* __restrict__ agg) {
    int e = blockIdx.x * blockDim.x + threadIdx.x;
    if (e >= NE) return;
    int r = ei[e];        // source row
    int c = ei[NE + e];   // target col
    float norm = dis[r] * w[e] * dis[c];
    const float* xs = x + r * FT;
    float* ad = agg + c * FT;
#pragma unroll
    for (int k = 0; k < FT; ++k) atomicAdd(&ad[k], norm * xs[k]);
}

// Compose M_z[f,d] = sum_c W_z[f,c]*Wlz[d,c]; beta_z[d] = blz[d] + sum_c b_z[c]*Wlz[d,c]
__global__ void k_weights(const float* __restrict__ Wz, const float* __restrict__ bz,
                          const float* __restrict__ Wh, const float* __restrict__ bh,
                          const float* __restrict__ Wlz, const float* __restrict__ blz,
                          const float* __restrict__ Wlh, const float* __restrict__ blh,
                          float* __restrict__ Mz, float* __restrict__ betaz,
                          float* __restrict__ Mh, float* __restrict__ betah) {
    int idx = blockIdx.x * blockDim.x + threadIdx.x;
    if (idx < 2400) {
        int f = idx / NC, d = idx % NC;
        const float* wr = Wz + f * NC;
        const float* lr = Wlz + d * (2 * NC);
        float s = 0.f;
        for (int c = 0; c < NC; ++c) s += wr[c] * lr[c];
        Mz[idx] = s;
    } else if (idx < 4800) {
        int j = idx - 2400;
        int f = j / NC, d = j % NC;
        const float* wr = Wh + f * NC;
        const float* lr = Wlh + d * (2 * NC);
        float s = 0.f;
        for (int c = 0; c < NC; ++c) s += wr[c] * lr[c];
        Mh[j] = s;
    } else if (idx < 5400) {
        int d = idx - 4800;
        const float* lr = Wlz + d * (2 * NC);
        float s = blz[d];
        for (int c = 0; c < NC; ++c) s += bz[c] * lr[c];
        betaz[d] = s;
    } else if (idx < 6000) {
        int d = idx - 5400;
        const float* lr = Wlh + d * (2 * NC);
        float s = blh[d];
        for (int c = 0; c < NC; ++c) s += bh[c] * lr[c];
        betah[d] = s;
    }
}

// One block per node: gates + temporal attention + ReLU + head matmul.
__global__ __launch_bounds__(256) void k_main(
        const float* __restrict__ agg,
        const float* __restrict__ Mz, const float* __restrict__ betaz,
        const float* __restrict__ Mh, const float* __restrict__ betah,
        const float* __restrict__ att,
        const float* __restrict__ Whead, const float* __restrict__ bhead,
        float* __restrict__ out) {
    int n = blockIdx.x;
    int tid = threadIdx.x;

    __shared__ float agg_s[FT];
    __shared__ float red[4][NT];

    if (tid < FT) agg_s[tid] = agg[n * FT + tid];

    // redundant per-thread softmax over att (12 elems)
    float a[NT];
#pragma unroll
    for (int t = 0; t < NT; ++t) a[t] = att[t];
    float m = a[0];
#pragma unroll
    for (int t = 1; t < NT; ++t) m = fmaxf(m, a[t]);
    float e[NT];
    float ssum = 0.f;
#pragma unroll
    for (int t = 0; t < NT; ++t) { e[t] = __expf(a[t] - m); ssum += e[t]; }
    float inv = 1.f / ssum;

    __syncthreads();

    float outp[NT];
#pragma unroll
    for (int t = 0; t < NT; ++t) outp[t] = 0.f;

    for (int d = tid; d < NC; d += 256) {
        float mz0 = Mz[0 * NC + d], mz1 = Mz[1 * NC + d], mz2 = Mz[2 * NC + d], mz3 = Mz[3 * NC + d];
        float mh0 = Mh[0 * NC + d], mh1 = Mh[1 * NC + d], mh2 = Mh[2 * NC + d], mh3 = Mh[3 * NC + d];
        float Bz = betaz[d], Bh = betah[d];
        float hacc = 0.f;
#pragma unroll
        for (int t = 0; t < NT; ++t) {
            float a0 = agg_s[0 * NT + t];
            float a1 = agg_s[1 * NT + t];
            float a2 = agg_s[2 * NT + t];
            float a3 = agg_s[3 * NT + t];
            float sz = Bz + a0 * mz0 + a1 * mz1 + a2 * mz2 + a3 * mz3;
            float sh = Bh + a0 * mh0 + a1 * mh1 + a2 * mh2 + a3 * mh3;
            float z = 1.f / (1.f + __expf(-sz));
            float ht = tanhf(sh);
            hacc += e[t] * (1.f - z) * ht;
        }
        hacc *= inv;
        float r = fmaxf(hacc, 0.f);
#pragma unroll
        for (int t = 0; t < NT; ++t) outp[t] += r * Whead[t * NC + d];
    }

    // wave64 reduction, then cross-wave via LDS
#pragma unroll
    for (int t = 0; t < NT; ++t) {
#pragma unroll
        for (int off = 32; off > 0; off >>= 1)
            outp[t] += __shfl_down(outp[t], off, 64);
    }
    int wave = tid >> 6, lane = tid & 63;
    if (lane == 0) {
#pragma unroll
        for (int t = 0; t < NT; ++t) red[wave][t] = outp[t];
    }
    __syncthreads();
    if (tid < NT) {
        float s = red[0][tid] + red[1][tid] + red[2][tid] + red[3][tid] + bhead[tid];
        out[n * NT + tid] = s;
    }
}

extern "C" void kernel_launch(void* const* d_in, const int* in_sizes, int n_in,
                              void* d_out, int out_size, void* d_ws, size_t ws_size,
                              hipStream_t stream) {
    const float* x     = (const float*)d_in[0];
    const int*   ei    = (const int*)d_in[1];
    const float* ea    = (const float*)d_in[2];
    const float* Wz    = (const float*)d_in[3];
    const float* bz    = (const float*)d_in[4];
    const float* Wh    = (const float*)d_in[7];
    const float* bh    = (const float*)d_in[8];
    const float* Wlz   = (const float*)d_in[9];
    const float* blz   = (const float*)d_in[10];
    const float* Wlh   = (const float*)d_in[13];
    const float* blh   = (const float*)d_in[14];
    const float* att   = (const float*)d_in[15];
    const float* Whead = (const float*)d_in[16];
    const float* bhead = (const float*)d_in[17];
    float* out = (float*)d_out;

    float* ws    = (float*)d_ws;
    float* dis   = ws;
    float* agg   = ws + 5000;
    float* Mz    = ws + 245000;
    float* betaz = ws + 247400;
    float* Mh    = ws + 248000;
    float* betah = ws + 250400;

    k_deg_init<<<(NN + 255) / 256, 256, 0, stream>>>(dis);
    k_deg_acc<<<(NE + 255) / 256, 256, 0, stream>>>(ei, ea, dis);
    k_dis<<<(NN + 255) / 256, 256, 0, stream>>>(dis);
    k_self<<<(NN * FT + 255) / 256, 256, 0, stream>>>(x, dis, agg);
    k_edge<<<(NE + 255) / 256, 256, 0, stream>>>(ei, ea, x, dis, agg);
    k_weights<<<(6000 + 255) / 256, 256, 0, stream>>>(Wz, bz, Wh, bh, Wlz, blz, Wlh, blh,
                                                      Mz, betaz, Mh, betah);
    k_main<<<NN, 256, 0, stream>>>(agg, Mz, betaz, Mh, betah, att, Whead, bhead, out);
}

// Round 2
// 175.502 us; speedup vs baseline: 3.0161x; 3.0161x over previous
//
#include <hip/hip_runtime.h>

#define NN 5000
#define NF 4
#define NT 12
#define NC 600
#define NE 160000
#define FT 48   // NF*NT

// ws layout (float offsets):
//   dis   [0,      5000)
//   cnt   [5000,  10000)   int: per-target edge count, reused as fill ctr
//   base  [10000, 15001)   int: CSR offsets
//   esrc  [16000, 176000)  int: source node per bucketed edge
//   enrm  [176000,336000)  float: norm per bucketed edge
//   agg   [336000,576000)
//   Mz    [576000,578400)  betaz [578400,579000)
//   Mh    [579000,581400)  betah [581400,582000)

__global__ void k_init(float* __restrict__ deg, int* __restrict__ cnt) {
    int i = blockIdx.x * blockDim.x + threadIdx.x;
    if (i < NN) { deg[i] = 1.0f; cnt[i] = 0; }   // self-loop weight 1
}

__global__ void k_deg_cnt(const int* __restrict__ ei, const float* __restrict__ w,
                          float* __restrict__ deg, int* __restrict__ cnt) {
    int e = blockIdx.x * blockDim.x + threadIdx.x;
    if (e < NE) {
        int c = ei[NE + e];
        atomicAdd(&deg[c], w[e]);
        atomicAdd(&cnt[c], 1);
    }
}

__global__ void k_dis(float* __restrict__ deg) {
    int i = blockIdx.x * blockDim.x + threadIdx.x;
    if (i < NN) { float d = deg[i]; deg[i] = d > 0.f ? rsqrtf(d) : 0.f; }
}

// single-block exclusive scan of cnt[0..NN) -> base; also zero fill (cnt reuse)
#define SCAN_CHUNK 20
__global__ __launch_bounds__(256) void k_scan(int* __restrict__ cnt, int* __restrict__ base) {
    __shared__ int part[256];
    int t = threadIdx.x;
    int start = t * SCAN_CHUNK;
    int s = 0;
#pragma unroll
    for (int k = 0; k < SCAN_CHUNK; ++k) {
        int idx = start + k;
        if (idx < NN) s += cnt[idx];
    }
    part[t] = s;
    __syncthreads();
    for (int off = 1; off < 256; off <<= 1) {
        int v = (t >= off) ? part[t - off] : 0;
        __syncthreads();
        part[t] += v;
        __syncthreads();
    }
    int running = (t == 0) ? 0 : part[t - 1];
#pragma unroll
    for (int k = 0; k < SCAN_CHUNK; ++k) {
        int idx = start + k;
        if (idx < NN) {
            base[idx] = running;
            running += cnt[idx];
            cnt[idx] = 0;           // becomes fill counter
        }
    }
    if (t == 255) base[NN] = part[255];
}

__global__ void k_scatter(const int* __restrict__ ei, const float* __restrict__ w,
                          const float* __restrict__ dis,
                          const int* __restrict__ base, int* __restrict__ fill,
                          int* __restrict__ esrc, float* __restrict__ enrm) {
    int e = blockIdx.x * blockDim.x + threadIdx.x;
    if (e >= NE) return;
    int r = ei[e];
    int c = ei[NE + e];
    int pos = base[c] + atomicAdd(&fill[c], 1);
    esrc[pos] = r;
    enrm[pos] = dis[r] * w[e] * dis[c];
}

// one 64-thread block per node: gather incident edges, accumulate agg in regs
__global__ __launch_bounds__(64) void k_gather(
        const float* __restrict__ x, const float* __restrict__ dis,
        const int* __restrict__ base,
        const int* __restrict__ esrc, const float* __restrict__ enrm,
        float* __restrict__ agg) {
    int n = blockIdx.x;
    int lane = threadIdx.x;
    int b0 = base[n], b1 = base[n + 1];
    float di = dis[n];
    float acc = 0.f;
    if (lane < FT) acc = di * di * x[n * FT + lane];
    int j = b0;
    for (; j + 3 < b1; j += 4) {
        int s0 = esrc[j], s1 = esrc[j + 1], s2 = esrc[j + 2], s3 = esrc[j + 3];
        float n0 = enrm[j], n1 = enrm[j + 1], n2 = enrm[j + 2], n3 = enrm[j + 3];
        if (lane < FT) {
            acc += n0 * x[s0 * FT + lane];
            acc += n1 * x[s1 * FT + lane];
            acc += n2 * x[s2 * FT + lane];
            acc += n3 * x[s3 * FT + lane];
        }
    }
    for (; j < b1; ++j) {
        int s0 = esrc[j];
        float n0 = enrm[j];
        if (lane < FT) acc += n0 * x[s0 * FT + lane];
    }
    if (lane < FT) agg[n * FT + lane] = acc;
}

// Compose M_z[f,d] = sum_c W_z[f,c]*Wlz[d,c]; beta_z[d] = blz[d] + sum_c b_z[c]*Wlz[d,c]
__global__ void k_weights(const float* __restrict__ Wz, const float* __restrict__ bz,
                          const float* __restrict__ Wh, const float* __restrict__ bh,
                          const float* __restrict__ Wlz, const float* __restrict__ blz,
                          const float* __restrict__ Wlh, const float* __restrict__ blh,
                          float* __restrict__ Mz, float* __restrict__ betaz,
                          float* __restrict__ Mh, float* __restrict__ betah) {
    int idx = blockIdx.x * blockDim.x + threadIdx.x;
    if (idx < 2400) {
        int f = idx / NC, d = idx % NC;
        const float* wr = Wz + f * NC;
        const float* lr = Wlz + d * (2 * NC);
        float s = 0.f;
        for (int c = 0; c < NC; ++c) s += wr[c] * lr[c];
        Mz[idx] = s;
    } else if (idx < 4800) {
        int j = idx - 2400;
        int f = j / NC, d = j % NC;
        const float* wr = Wh + f * NC;
        const float* lr = Wlh + d * (2 * NC);
        float s = 0.f;
        for (int c = 0; c < NC; ++c) s += wr[c] * lr[c];
        Mh[j] = s;
    } else if (idx < 5400) {
        int d = idx - 4800;
        const float* lr = Wlz + d * (2 * NC);
        float s = blz[d];
        for (int c = 0; c < NC; ++c) s += bz[c] * lr[c];
        betaz[d] = s;
    } else if (idx < 6000) {
        int d = idx - 5400;
        const float* lr = Wlh + d * (2 * NC);
        float s = blh[d];
        for (int c = 0; c < NC; ++c) s += bh[c] * lr[c];
        betah[d] = s;
    }
}

// One block per node: gates + temporal attention + ReLU + head matmul.
__global__ __launch_bounds__(256) void k_main(
        const float* __restrict__ agg,
        const float* __restrict__ Mz, const float* __restrict__ betaz,
        const float* __restrict__ Mh, const float* __restrict__ betah,
        const float* __restrict__ att,
        const float* __restrict__ Whead, const float* __restrict__ bhead,
        float* __restrict__ out) {
    int n = blockIdx.x;
    int tid = threadIdx.x;

    __shared__ float agg_s[FT];
    __shared__ float red[4][NT];

    if (tid < FT) agg_s[tid] = agg[n * FT + tid];

    float a[NT];
#pragma unroll
    for (int t = 0; t < NT; ++t) a[t] = att[t];
    float m = a[0];
#pragma unroll
    for (int t = 1; t < NT; ++t) m = fmaxf(m, a[t]);
    float e[NT];
    float ssum = 0.f;
#pragma unroll
    for (int t = 0; t < NT; ++t) { e[t] = __expf(a[t] - m); ssum += e[t]; }
    float inv = 1.f / ssum;

    __syncthreads();

    float outp[NT];
#pragma unroll
    for (int t = 0; t < NT; ++t) outp[t] = 0.f;

    for (int d = tid; d < NC; d += 256) {
        float mz0 = Mz[0 * NC + d], mz1 = Mz[1 * NC + d], mz2 = Mz[2 * NC + d], mz3 = Mz[3 * NC + d];
        float mh0 = Mh[0 * NC + d], mh1 = Mh[1 * NC + d], mh2 = Mh[2 * NC + d], mh3 = Mh[3 * NC + d];
        float Bz = betaz[d], Bh = betah[d];
        float hacc = 0.f;
#pragma unroll
        for (int t = 0; t < NT; ++t) {
            float a0 = agg_s[0 * NT + t];
            float a1 = agg_s[1 * NT + t];
            float a2 = agg_s[2 * NT + t];
            float a3 = agg_s[3 * NT + t];
            float sz = Bz + a0 * mz0 + a1 * mz1 + a2 * mz2 + a3 * mz3;
            float sh = Bh + a0 * mh0 + a1 * mh1 + a2 * mh2 + a3 * mh3;
            float z = 1.f / (1.f + __expf(-sz));
            float ht = tanhf(sh);
            hacc += e[t] * (1.f - z) * ht;
        }
        hacc *= inv;
        float r = fmaxf(hacc, 0.f);
#pragma unroll
        for (int t = 0; t < NT; ++t) outp[t] += r * Whead[t * NC + d];
    }

#pragma unroll
    for (int t = 0; t < NT; ++t) {
#pragma unroll
        for (int off = 32; off > 0; off >>= 1)
            outp[t] += __shfl_down(outp[t], off, 64);
    }
    int wave = tid >> 6, lane = tid & 63;
    if (lane == 0) {
#pragma unroll
        for (int t = 0; t < NT; ++t) red[wave][t] = outp[t];
    }
    __syncthreads();
    if (tid < NT) {
        float s = red[0][tid] + red[1][tid] + red[2][tid] + red[3][tid] + bhead[tid];
        out[n * NT + tid] = s;
    }
}

extern "C" void kernel_launch(void* const* d_in, const int* in_sizes, int n_in,
                              void* d_out, int out_size, void* d_ws, size_t ws_size,
                              hipStream_t stream) {
    const float* x     = (const float*)d_in[0];
    const int*   ei    = (const int*)d_in[1];
    const float* ea    = (const float*)d_in[2];
    const float* Wz    = (const float*)d_in[3];
    const float* bz    = (const float*)d_in[4];
    const float* Wh    = (const float*)d_in[7];
    const float* bh    = (const float*)d_in[8];
    const float* Wlz   = (const float*)d_in[9];
    const float* blz   = (const float*)d_in[10];
    const float* Wlh   = (const float*)d_in[13];
    const float* blh   = (const float*)d_in[14];
    const float* att   = (const float*)d_in[15];
    const float* Whead = (const float*)d_in[16];
    const float* bhead = (const float*)d_in[17];
    float* out = (float*)d_out;

    float* ws    = (float*)d_ws;
    float* dis   = ws;
    int*   cnt   = (int*)(ws + 5000);
    int*   base  = (int*)(ws + 10000);
    int*   esrc  = (int*)(ws + 16000);
    float* enrm  = ws + 176000;
    float* agg   = ws + 336000;
    float* Mz    = ws + 576000;
    float* betaz = ws + 578400;
    float* Mh    = ws + 579000;
    float* betah = ws + 581400;

    k_init<<<(NN + 255) / 256, 256, 0, stream>>>(dis, cnt);
    k_deg_cnt<<<(NE + 255) / 256, 256, 0, stream>>>(ei, ea, dis, cnt);
    k_dis<<<(NN + 255) / 256, 256, 0, stream>>>(dis);
    k_scan<<<1, 256, 0, stream>>>(cnt, base);
    k_scatter<<<(NE + 255) / 256, 256, 0, stream>>>(ei, ea, dis, base, cnt, esrc, enrm);
    k_weights<<<(6000 + 255) / 256, 256, 0, stream>>>(Wz, bz, Wh, bh, Wlz, blz, Wlh, blh,
                                                      Mz, betaz, Mh, betah);
    k_gather<<<NN, 64, 0, stream>>>(x, dis, base, esrc, enrm, agg);
    k_main<<<NN, 256, 0, stream>>>(agg, Mz, betaz, Mh, betah, att, Whead, bhead, out);
}

// Round 3
// 157.122 us; speedup vs baseline: 3.3689x; 1.1170x over previous
//
#include <hip/hip_runtime.h>

#define NN 5000
#define NF 4
#define NT 12
#define NC 600
#define NE 160000
#define FT 48   // NF*NT
#define LOG2E 1.4426950408889634f

// ws layout (float offsets):
//   dis   [0,      5000)
//   cnt   [5000,  10000)   int: per-target edge count, reused as fill ctr
//   base  [10000, 15001)   int: CSR offsets
//   esrc  [16000, 176000)  int: source node per bucketed edge
//   enrm  [176000,336000)  float: norm per bucketed edge
//   agg   [336000,576000)
//   Mz    [576000,578400)  betaz [578400,579000)
//   Mh    [579000,581400)  betah [581400,582000)
//   probs [582000,582012)

__global__ void k_init(float* __restrict__ deg, int* __restrict__ cnt) {
    int i = blockIdx.x * blockDim.x + threadIdx.x;
    if (i < NN) { deg[i] = 1.0f; cnt[i] = 0; }   // self-loop weight 1
}

__global__ void k_deg_cnt(const int* __restrict__ ei, const float* __restrict__ w,
                          float* __restrict__ deg, int* __restrict__ cnt) {
    int e = blockIdx.x * blockDim.x + threadIdx.x;
    if (e < NE) {
        int c = ei[NE + e];
        atomicAdd(&deg[c], w[e]);
        atomicAdd(&cnt[c], 1);
    }
}

__global__ void k_dis(float* __restrict__ deg) {
    int i = blockIdx.x * blockDim.x + threadIdx.x;
    if (i < NN) { float d = deg[i]; deg[i] = d > 0.f ? rsqrtf(d) : 0.f; }
}

// single-block exclusive scan of cnt[0..NN) -> base; also zero fill (cnt reuse)
#define SCAN_CHUNK 20
__global__ __launch_bounds__(256) void k_scan(int* __restrict__ cnt, int* __restrict__ base) {
    __shared__ int part[256];
    int t = threadIdx.x;
    int start = t * SCAN_CHUNK;
    int s = 0;
#pragma unroll
    for (int k = 0; k < SCAN_CHUNK; ++k) {
        int idx = start + k;
        if (idx < NN) s += cnt[idx];
    }
    part[t] = s;
    __syncthreads();
    for (int off = 1; off < 256; off <<= 1) {
        int v = (t >= off) ? part[t - off] : 0;
        __syncthreads();
        part[t] += v;
        __syncthreads();
    }
    int running = (t == 0) ? 0 : part[t - 1];
#pragma unroll
    for (int k = 0; k < SCAN_CHUNK; ++k) {
        int idx = start + k;
        if (idx < NN) {
            base[idx] = running;
            running += cnt[idx];
            cnt[idx] = 0;           // becomes fill counter
        }
    }
    if (t == 255) base[NN] = part[255];
}

__global__ void k_scatter(const int* __restrict__ ei, const float* __restrict__ w,
                          const float* __restrict__ dis,
                          const int* __restrict__ base, int* __restrict__ fill,
                          int* __restrict__ esrc, float* __restrict__ enrm) {
    int e = blockIdx.x * blockDim.x + threadIdx.x;
    if (e >= NE) return;
    int r = ei[e];
    int c = ei[NE + e];
    int pos = base[c] + atomicAdd(&fill[c], 1);
    esrc[pos] = r;
    enrm[pos] = dis[r] * w[e] * dis[c];
}

// one 64-thread block per node: gather incident edges, accumulate agg in regs
__global__ __launch_bounds__(64) void k_gather(
        const float* __restrict__ x, const float* __restrict__ dis,
        const int* __restrict__ base,
        const int* __restrict__ esrc, const float* __restrict__ enrm,
        float* __restrict__ agg) {
    int n = blockIdx.x;
    int lane = threadIdx.x;
    int b0 = base[n], b1 = base[n + 1];
    float di = dis[n];
    float acc = 0.f;
    if (lane < FT) acc = di * di * x[n * FT + lane];
    int j = b0;
    for (; j + 3 < b1; j += 4) {
        int s0 = esrc[j], s1 = esrc[j + 1], s2 = esrc[j + 2], s3 = esrc[j + 3];
        float n0 = enrm[j], n1 = enrm[j + 1], n2 = enrm[j + 2], n3 = enrm[j + 3];
        if (lane < FT) {
            acc += n0 * x[s0 * FT + lane];
            acc += n1 * x[s1 * FT + lane];
            acc += n2 * x[s2 * FT + lane];
            acc += n3 * x[s3 * FT + lane];
        }
    }
    for (; j < b1; ++j) {
        int s0 = esrc[j];
        float n0 = enrm[j];
        if (lane < FT) acc += n0 * x[s0 * FT + lane];
    }
    if (lane < FT) agg[n * FT + lane] = acc;
}

// Compose M_z[f,d] = sum_c W_z[f,c]*Wlz[d,c], pre-scaled by LOG2E (sigmoid arg)
// and M_h pre-scaled by 2*LOG2E (tanh arg). Also softmax(att) -> probs.
__global__ void k_weights(const float* __restrict__ Wz, const float* __restrict__ bz,
                          const float* __restrict__ Wh, const float* __restrict__ bh,
                          const float* __restrict__ Wlz, const float* __restrict__ blz,
                          const float* __restrict__ Wlh, const float* __restrict__ blh,
                          const float* __restrict__ att,
                          float* __restrict__ Mz, float* __restrict__ betaz,
                          float* __restrict__ Mh, float* __restrict__ betah,
                          float* __restrict__ probs) {
    int idx = blockIdx.x * blockDim.x + threadIdx.x;
    if (idx < 2400) {
        int f = idx / NC, d = idx % NC;
        const float* wr = Wz + f * NC;
        const float* lr = Wlz + d * (2 * NC);
        float s = 0.f;
        for (int c = 0; c < NC; ++c) s += wr[c] * lr[c];
        Mz[idx] = s * LOG2E;
    } else if (idx < 4800) {
        int j = idx - 2400;
        int f = j / NC, d = j % NC;
        const float* wr = Wh + f * NC;
        const float* lr = Wlh + d * (2 * NC);
        float s = 0.f;
        for (int c = 0; c < NC; ++c) s += wr[c] * lr[c];
        Mh[j] = s * (2.0f * LOG2E);
    } else if (idx < 5400) {
        int d = idx - 4800;
        const float* lr = Wlz + d * (2 * NC);
        float s = blz[d];
        for (int c = 0; c < NC; ++c) s += bz[c] * lr[c];
        betaz[d] = s * LOG2E;
    } else if (idx < 6000) {
        int d = idx - 5400;
        const float* lr = Wlh + d * (2 * NC);
        float s = blh[d];
        for (int c = 0; c < NC; ++c) s += bh[c] * lr[c];
        betah[d] = s * (2.0f * LOG2E);
    } else if (idx < 6000 + NT) {
        int t = idx - 6000;
        float m = att[0];
        for (int k = 1; k < NT; ++k) m = fmaxf(m, att[k]);
        float ssum = 0.f;
        for (int k = 0; k < NT; ++k) ssum += __expf(att[k] - m);
        probs[t] = __expf(att[t] - m) / ssum;
    }
}

// One block per node: gates + temporal attention + ReLU + head matmul.
// (1-z)*tanh(h) = (e^v - 1) / ((1+e^u)(1+e^v)), u = sz (pre-scaled to exp2),
// v = 2*sh (pre-scaled to exp2). 2 exp2 + 1 rcp per (d,t).
__global__ __launch_bounds__(256) void k_main(
        const float* __restrict__ agg,
        const float* __restrict__ Mz, const float* __restrict__ betaz,
        const float* __restrict__ Mh, const float* __restrict__ betah,
        const float* __restrict__ probs,
        const float* __restrict__ Whead, const float* __restrict__ bhead,
        float* __restrict__ out) {
    int n = blockIdx.x;
    int tid = threadIdx.x;

    __shared__ float agg_s[FT];
    __shared__ float red[4][NT];

    if (tid < FT) agg_s[tid] = agg[n * FT + tid];

    float p[NT];
#pragma unroll
    for (int t = 0; t < NT; ++t) p[t] = probs[t];

    __syncthreads();

    float outp[NT];
#pragma unroll
    for (int t = 0; t < NT; ++t) outp[t] = 0.f;

    for (int d = tid; d < NC; d += 256) {
        float mz0 = Mz[0 * NC + d], mz1 = Mz[1 * NC + d], mz2 = Mz[2 * NC + d], mz3 = Mz[3 * NC + d];
        float mh0 = Mh[0 * NC + d], mh1 = Mh[1 * NC + d], mh2 = Mh[2 * NC + d], mh3 = Mh[3 * NC + d];
        float Bz = betaz[d], Bh = betah[d];
        float hacc = 0.f;
#pragma unroll
        for (int t = 0; t < NT; ++t) {
            float a0 = agg_s[0 * NT + t];
            float a1 = agg_s[1 * NT + t];
            float a2 = agg_s[2 * NT + t];
            float a3 = agg_s[3 * NT + t];
            float u = fmaf(a3, mz3, fmaf(a2, mz2, fmaf(a1, mz1, fmaf(a0, mz0, Bz))));
            float v = fmaf(a3, mh3, fmaf(a2, mh2, fmaf(a1, mh1, fmaf(a0, mh0, Bh))));
            float eu = exp2f(u);
            float ev = exp2f(v);
            float rden = __builtin_amdgcn_rcpf((1.f + eu) * (1.f + ev));
            float num = p[t] * (ev - 1.f);
            hacc = fmaf(num, rden, hacc);
        }
        float r = fmaxf(hacc, 0.f);
#pragma unroll
        for (int t = 0; t < NT; ++t) outp[t] = fmaf(r, Whead[t * NC + d], outp[t]);
    }

#pragma unroll
    for (int t = 0; t < NT; ++t) {
#pragma unroll
        for (int off = 32; off > 0; off >>= 1)
            outp[t] += __shfl_down(outp[t], off, 64);
    }
    int wave = tid >> 6, lane = tid & 63;
    if (lane == 0) {
#pragma unroll
        for (int t = 0; t < NT; ++t) red[wave][t] = outp[t];
    }
    __syncthreads();
    if (tid < NT) {
        float s = red[0][tid] + red[1][tid] + red[2][tid] + red[3][tid] + bhead[tid];
        out[n * NT + tid] = s;
    }
}

extern "C" void kernel_launch(void* const* d_in, const int* in_sizes, int n_in,
                              void* d_out, int out_size, void* d_ws, size_t ws_size,
                              hipStream_t stream) {
    const float* x     = (const float*)d_in[0];
    const int*   ei    = (const int*)d_in[1];
    const float* ea    = (const float*)d_in[2];
    const float* Wz    = (const float*)d_in[3];
    const float* bz    = (const float*)d_in[4];
    const float* Wh    = (const float*)d_in[7];
    const float* bh    = (const float*)d_in[8];
    const float* Wlz   = (const float*)d_in[9];
    const float* blz   = (const float*)d_in[10];
    const float* Wlh   = (const float*)d_in[13];
    const float* blh   = (const float*)d_in[14];
    const float* att   = (const float*)d_in[15];
    const float* Whead = (const float*)d_in[16];
    const float* bhead = (const float*)d_in[17];
    float* out = (float*)d_out;

    float* ws    = (float*)d_ws;
    float* dis   = ws;
    int*   cnt   = (int*)(ws + 5000);
    int*   base  = (int*)(ws + 10000);
    int*   esrc  = (int*)(ws + 16000);
    float* enrm  = ws + 176000;
    float* agg   = ws + 336000;
    float* Mz    = ws + 576000;
    float* betaz = ws + 578400;
    float* Mh    = ws + 579000;
    float* betah = ws + 581400;
    float* probs = ws + 582000;

    k_init<<<(NN + 255) / 256, 256, 0, stream>>>(dis, cnt);
    k_deg_cnt<<<(NE + 255) / 256, 256, 0, stream>>>(ei, ea, dis, cnt);
    k_dis<<<(NN + 255) / 256, 256, 0, stream>>>(dis);
    k_scan<<<1, 256, 0, stream>>>(cnt, base);
    k_scatter<<<(NE + 255) / 256, 256, 0, stream>>>(ei, ea, dis, base, cnt, esrc, enrm);
    k_weights<<<(6000 + NT + 255) / 256, 256, 0, stream>>>(Wz, bz, Wh, bh, Wlz, blz, Wlh, blh,
                                                           att, Mz, betaz, Mh, betah, probs);
    k_gather<<<NN, 64, 0, stream>>>(x, dis, base, esrc, enrm, agg);
    k_main<<<NN, 256, 0, stream>>>(agg, Mz, betaz, Mh, betah, probs, Whead, bhead, out);
}

// Round 4
// 93.861 us; speedup vs baseline: 5.6394x; 1.6740x over previous
//
#include <hip/hip_runtime.h>

#define NN 5000
#define NF 4
#define NT 12
#define NC 600
#define NE 160000
#define FT 48   // NF*NT
#define LOG2E 1.4426950408889634f

// ws layout (float offsets):
//   dis   [0,      5000)
//   cnt   [5000,  10000)   int: per-target edge count
//   base  [10000, 15001)   int: CSR offsets
//   rank  [16000, 176000)  int: edge rank within its target bucket
//   eid   [176000,336000)  int: bucketed edge id (CSR adjacency)
//   agg   [336000,576000)
//   Mz    [576000,578400)  betaz [578400,579000)
//   Mh    [579000,581400)  betah [581400,582000)
//   probs [582000,582012)

__global__ void k_init(int* __restrict__ cnt) {
    int i = blockIdx.x * blockDim.x + threadIdx.x;
    if (i < NN) cnt[i] = 0;
}

// rank within bucket via atomic; coalesced rank write (no dependent scatter)
__global__ void k_count(const int* __restrict__ ei, int* __restrict__ cnt,
                        int* __restrict__ rank) {
    int e = blockIdx.x * blockDim.x + threadIdx.x;
    if (e < NE) rank[e] = atomicAdd(&cnt[ei[NE + e]], 1);
}

// single-block exclusive scan of cnt[0..NN) -> base
#define SCAN_CHUNK 20
__global__ __launch_bounds__(256) void k_scan(const int* __restrict__ cnt,
                                              int* __restrict__ base) {
    __shared__ int part[256];
    int t = threadIdx.x;
    int start = t * SCAN_CHUNK;
    int s = 0;
#pragma unroll
    for (int k = 0; k < SCAN_CHUNK; ++k) {
        int idx = start + k;
        if (idx < NN) s += cnt[idx];
    }
    part[t] = s;
    __syncthreads();
    for (int off = 1; off < 256; off <<= 1) {
        int v = (t >= off) ? part[t - off] : 0;
        __syncthreads();
        part[t] += v;
        __syncthreads();
    }
    int running = (t == 0) ? 0 : part[t - 1];
#pragma unroll
    for (int k = 0; k < SCAN_CHUNK; ++k) {
        int idx = start + k;
        if (idx < NN) {
            base[idx] = running;
            running += cnt[idx];
        }
    }
    if (t == 255) base[NN] = part[255];
}

// deterministic-position scatter: ONE 4B store per edge, no atomics
__global__ void k_scatter(const int* __restrict__ ei, const int* __restrict__ base,
                          const int* __restrict__ rank, int* __restrict__ eid) {
    int e = blockIdx.x * blockDim.x + threadIdx.x;
    if (e < NE) eid[base[ei[NE + e]] + rank[e]] = e;
}

// per-node degree from bucketed edges (gather reads), then dis = rsqrt(deg)
__global__ __launch_bounds__(64) void k_deg_dis(const float* __restrict__ w,
                                                const int* __restrict__ base,
                                                const int* __restrict__ eid,
                                                float* __restrict__ dis) {
    int n = blockIdx.x;
    int lane = threadIdx.x;
    int b0 = base[n], b1 = base[n + 1];
    float s = 0.f;
    for (int j = b0 + lane; j < b1; j += 64) s += w[eid[j]];
#pragma unroll
    for (int off = 32; off > 0; off >>= 1) s += __shfl_down(s, off, 64);
    if (lane == 0) dis[n] = rsqrtf(1.0f + s);   // self-loop weight 1 -> deg>0 always
}

// one 64-thread block per node: gather incident edges, accumulate agg in regs.
// agg[n] = dis[n] * ( dis[n]*x[n] + sum_j dis[s_j]*w_j*x[s_j] )
__global__ __launch_bounds__(64) void k_gather(
        const float* __restrict__ x, const float* __restrict__ dis,
        const float* __restrict__ w, const int* __restrict__ ei,
        const int* __restrict__ base, const int* __restrict__ eid,
        float* __restrict__ agg) {
    int n = blockIdx.x;
    int lane = threadIdx.x;
    int b0 = base[n], b1 = base[n + 1];
    float dn = dis[n];
    float acc = 0.f;
    if (lane < FT) acc = dn * x[n * FT + lane];
    int j = b0;
    for (; j + 3 < b1; j += 4) {
        int e0 = eid[j], e1 = eid[j + 1], e2 = eid[j + 2], e3 = eid[j + 3];
        int s0 = ei[e0], s1 = ei[e1], s2 = ei[e2], s3 = ei[e3];
        float n0 = dis[s0] * w[e0];
        float n1 = dis[s1] * w[e1];
        float n2 = dis[s2] * w[e2];
        float n3 = dis[s3] * w[e3];
        if (lane < FT) {
            acc += n0 * x[s0 * FT + lane];
            acc += n1 * x[s1 * FT + lane];
            acc += n2 * x[s2 * FT + lane];
            acc += n3 * x[s3 * FT + lane];
        }
    }
    for (; j < b1; ++j) {
        int e0 = eid[j];
        int s0 = ei[e0];
        float n0 = dis[s0] * w[e0];
        if (lane < FT) acc += n0 * x[s0 * FT + lane];
    }
    if (lane < FT) agg[n * FT + lane] = dn * acc;
}

// One wave per output element. Outputs:
//   [0,2400)    Mz[f*NC+d]    = LOG2E   * sum_c Wz[f,c]*Wlz[d,c]
//   [2400,4800) Mh[j]         = 2*LOG2E * sum_c Wh[f,c]*Wlh[d,c]
//   [4800,5400) betaz[d]      = LOG2E   * (blz[d] + sum_c bz[c]*Wlz[d,c])
//   [5400,6000) betah[d]      = 2*LOG2E * (blh[d] + sum_c bh[c]*Wlh[d,c])
//   [6000,6012) probs[t]      = softmax(att)[t]
__global__ __launch_bounds__(256) void k_weights(
        const float* __restrict__ Wz, const float* __restrict__ bz,
        const float* __restrict__ Wh, const float* __restrict__ bh,
        const float* __restrict__ Wlz, const float* __restrict__ blz,
        const float* __restrict__ Wlh, const float* __restrict__ blh,
        const float* __restrict__ att,
        float* __restrict__ Mz, float* __restrict__ betaz,
        float* __restrict__ Mh, float* __restrict__ betah,
        float* __restrict__ probs) {
    int wid = blockIdx.x * 4 + (threadIdx.x >> 6);   // global wave id
    int lane = threadIdx.x & 63;
    if (wid >= 6012) return;

    if (wid < 6000) {
        const float* va;
        const float* vb;
        float scale, bias = 0.f;
        int outi = wid;
        if (wid < 2400) {
            int f = wid / NC, d = wid % NC;
            va = Wz + f * NC; vb = Wlz + d * (2 * NC); scale = LOG2E;
        } else if (wid < 4800) {
            int j = wid - 2400;
            int f = j / NC, d = j % NC;
            va = Wh + f * NC; vb = Wlh + d * (2 * NC); scale = 2.0f * LOG2E;
        } else if (wid < 5400) {
            int d = wid - 4800;
            va = bz; vb = Wlz + d * (2 * NC); scale = LOG2E; bias = blz[d];
        } else {
            int d = wid - 5400;
            va = bh; vb = Wlh + d * (2 * NC); scale = 2.0f * LOG2E; bias = blh[d];
        }
        float s = 0.f;
        for (int c = lane; c < NC; c += 64) s = fmaf(va[c], vb[c], s);
#pragma unroll
        for (int off = 32; off > 0; off >>= 1) s += __shfl_down(s, off, 64);
        if (lane == 0) {
            float r = scale * (bias + s);
            if (wid < 2400) Mz[outi] = r;
            else if (wid < 4800) Mh[outi - 2400] = r;
            else if (wid < 5400) betaz[outi - 4800] = r;
            else betah[outi - 5400] = r;
        }
    } else if (lane == 0) {
        int t = wid - 6000;
        float m = att[0];
        for (int k = 1; k < NT; ++k) m = fmaxf(m, att[k]);
        float ssum = 0.f;
        for (int k = 0; k < NT; ++k) ssum += __expf(att[k] - m);
        probs[t] = __expf(att[t] - m) / ssum;
    }
}

// One block per node: gates + temporal attention + ReLU + head matmul.
// (1-z)*tanh(h) = (e^v - 1) / ((1+e^u)(1+e^v)), u,v pre-scaled for exp2.
__global__ __launch_bounds__(256) void k_main(
        const float* __restrict__ agg,
        const float* __restrict__ Mz, const float* __restrict__ betaz,
        const float* __restrict__ Mh, const float* __restrict__ betah,
        const float* __restrict__ probs,
        const float* __restrict__ Whead, const float* __restrict__ bhead,
        float* __restrict__ out) {
    int n = blockIdx.x;
    int tid = threadIdx.x;

    __shared__ float agg_s[FT];
    __shared__ float red[4][NT];

    if (tid < FT) agg_s[tid] = agg[n * FT + tid];

    float p[NT];
#pragma unroll
    for (int t = 0; t < NT; ++t) p[t] = probs[t];

    __syncthreads();

    float outp[NT];
#pragma unroll
    for (int t = 0; t < NT; ++t) outp[t] = 0.f;

    for (int d = tid; d < NC; d += 256) {
        float mz0 = Mz[0 * NC + d], mz1 = Mz[1 * NC + d], mz2 = Mz[2 * NC + d], mz3 = Mz[3 * NC + d];
        float mh0 = Mh[0 * NC + d], mh1 = Mh[1 * NC + d], mh2 = Mh[2 * NC + d], mh3 = Mh[3 * NC + d];
        float Bz = betaz[d], Bh = betah[d];
        float hacc = 0.f;
#pragma unroll
        for (int t = 0; t < NT; ++t) {
            float a0 = agg_s[0 * NT + t];
            float a1 = agg_s[1 * NT + t];
            float a2 = agg_s[2 * NT + t];
            float a3 = agg_s[3 * NT + t];
            float u = fmaf(a3, mz3, fmaf(a2, mz2, fmaf(a1, mz1, fmaf(a0, mz0, Bz))));
            float v = fmaf(a3, mh3, fmaf(a2, mh2, fmaf(a1, mh1, fmaf(a0, mh0, Bh))));
            float eu = exp2f(u);
            float ev = exp2f(v);
            float rden = __builtin_amdgcn_rcpf((1.f + eu) * (1.f + ev));
            float num = p[t] * (ev - 1.f);
            hacc = fmaf(num, rden, hacc);
        }
        float r = fmaxf(hacc, 0.f);
#pragma unroll
        for (int t = 0; t < NT; ++t) outp[t] = fmaf(r, Whead[t * NC + d], outp[t]);
    }

#pragma unroll
    for (int t = 0; t < NT; ++t) {
#pragma unroll
        for (int off = 32; off > 0; off >>= 1)
            outp[t] += __shfl_down(outp[t], off, 64);
    }
    int wave = tid >> 6, lane = tid & 63;
    if (lane == 0) {
#pragma unroll
        for (int t = 0; t < NT; ++t) red[wave][t] = outp[t];
    }
    __syncthreads();
    if (tid < NT) {
        float s = red[0][tid] + red[1][tid] + red[2][tid] + red[3][tid] + bhead[tid];
        out[n * NT + tid] = s;
    }
}

extern "C" void kernel_launch(void* const* d_in, const int* in_sizes, int n_in,
                              void* d_out, int out_size, void* d_ws, size_t ws_size,
                              hipStream_t stream) {
    const float* x     = (const float*)d_in[0];
    const int*   ei    = (const int*)d_in[1];
    const float* ea    = (const float*)d_in[2];
    const float* Wz    = (const float*)d_in[3];
    const float* bz    = (const float*)d_in[4];
    const float* Wh    = (const float*)d_in[7];
    const float* bh    = (const float*)d_in[8];
    const float* Wlz   = (const float*)d_in[9];
    const float* blz   = (const float*)d_in[10];
    const float* Wlh   = (const float*)d_in[13];
    const float* blh   = (const float*)d_in[14];
    const float* att   = (const float*)d_in[15];
    const float* Whead = (const float*)d_in[16];
    const float* bhead = (const float*)d_in[17];
    float* out = (float*)d_out;

    float* ws    = (float*)d_ws;
    float* dis   = ws;
    int*   cnt   = (int*)(ws + 5000);
    int*   base  = (int*)(ws + 10000);
    int*   rank  = (int*)(ws + 16000);
    int*   eid   = (int*)(ws + 176000);
    float* agg   = ws + 336000;
    float* Mz    = ws + 576000;
    float* betaz = ws + 578400;
    float* Mh    = ws + 579000;
    float* betah = ws + 581400;
    float* probs = ws + 582000;

    k_init<<<(NN + 255) / 256, 256, 0, stream>>>(cnt);
    k_count<<<(NE + 255) / 256, 256, 0, stream>>>(ei, cnt, rank);
    k_scan<<<1, 256, 0, stream>>>(cnt, base);
    k_scatter<<<(NE + 255) / 256, 256, 0, stream>>>(ei, base, rank, eid);
    k_weights<<<(6012 + 3) / 4, 256, 0, stream>>>(Wz, bz, Wh, bh, Wlz, blz, Wlh, blh,
                                                  att, Mz, betaz, Mh, betah, probs);
    k_deg_dis<<<NN, 64, 0, stream>>>(ea, base, eid, dis);
    k_gather<<<NN, 64, 0, stream>>>(x, dis, ea, ei, base, eid, agg);
    k_main<<<NN, 256, 0, stream>>>(agg, Mz, betaz, Mh, betah, probs, Whead, bhead, out);
}